// Round 7
// baseline (307.506 us; speedup 1.0000x reference)
//
#include <hip/hip_runtime.h>
#include <hip/hip_bf16.h>
#include <stdint.h>

#define LQ 1024
#define BQ 2
#define AQ 14
#define KQ 30
#define EFQ 128
#define EDGE_IN 3152
#define KPAD 3200
#define NCHUNK 50
#define MTILE 128
#define ROWS (BQ*LQ*KQ)            /* 61440 */
#define EIDX_OFF (ROWS*EFQ)        /* 7864320 */

typedef __attribute__((ext_vector_type(8))) _Float16 half8;
typedef __attribute__((ext_vector_type(2))) _Float16 half2t;
typedef __attribute__((ext_vector_type(4))) float floatx4;
typedef unsigned long long ull;

static __device__ __forceinline__ uint32_t pkh(float a, float b) {
    auto h = __builtin_amdgcn_cvt_pkrtz(a, b);   // __fp16 ext_vector(2)
    return __builtin_bit_cast(uint32_t, h);
}
static __device__ __forceinline__ ull umin64(ull a, ull b) { return a < b ? a : b; }

// ---------------------------------------------------------------------------
// Kernel A v6 (unchanged): blocks 0..255 topk (8 rows/block, one wave per row,
// u64-packed keys); blocks 256..305: W fp32 -> f16 padded copy.
// ---------------------------------------------------------------------------
__global__ __launch_bounds__(512) void topk_kernel(
    const float* __restrict__ X, const float* __restrict__ mask,
    const float* __restrict__ W, float* __restrict__ out,
    int* __restrict__ idx_ws, _Float16* __restrict__ wpad)
{
    __shared__ float xs[LQ], ys[LQ], zs[LQ], ms[LQ];
    const int t = threadIdx.x;

    if (blockIdx.x >= 256) {                    // ---- merged wpad ----
        int base = (blockIdx.x - 256)*8192 + t; // 50 blocks x 8192 = 409600 exact
        #pragma unroll
        for (int r = 0; r < 16; ++r) {
            int idx = base + r*512;
            int n = idx / KPAD, f = idx - n*KPAD;
            float v = (f < EDGE_IN) ? W[(size_t)n*EDGE_IN + f] : 0.0f;
            wpad[idx] = (_Float16)v;
        }
        return;
    }

    const int w = t >> 6, lane = t & 63;
    const int row = blockIdx.x*8 + w;           // same b for whole block
    const int b = row >> 10, i = row & (LQ - 1);

    for (int j = t; j < LQ; j += 512) {
        size_t base = ((size_t)(b*LQ + j))*42 + 3;   // atom 1 (CA)
        xs[j] = X[base+0]; ys[j] = X[base+1]; zs[j] = X[base+2];
        ms[j] = mask[b*LQ + j];
    }
    __syncthreads();

    const float mif = ms[i];
    const double cx = (double)xs[i], cy = (double)ys[i], cz = (double)zs[i];

    double Dk[16]; float mf[16];
    bool allone = (mif == 1.0f);
    #pragma unroll
    for (int s = 0; s < 16; ++s) {
        int j = s*64 + lane;
        double dx = __dsub_rn(cx, (double)xs[j]);
        double dy = __dsub_rn(cy, (double)ys[j]);
        double dz = __dsub_rn(cz, (double)zs[j]);
        mf[s] = ms[j];
        Dk[s] = __dadd_rn(__dadd_rn(__dmul_rn(dx,dx), __dmul_rn(dy,dy)),
                          __dmul_rn(dz,dz));
        allone = allone && (mf[s] == 1.0f);
    }

    if (!__all(allone ? 1 : 0)) {
        // exact general path: D = mi*mj*sqrt(ssq+1e-6); key = D + 2(1-m2)*max(D)
        const double mi_d = (double)mif;
        double lm = 0.0;
        #pragma unroll
        for (int s = 0; s < 16; ++s) {
            double m2 = __dmul_rn(mi_d, (double)mf[s]);
            Dk[s] = __dmul_rn(m2, sqrt(__dadd_rn(Dk[s], 1e-6)));
            lm = fmax(lm, Dk[s]);
        }
        #pragma unroll
        for (int off = 32; off; off >>= 1) lm = fmax(lm, __shfl_xor(lm, off));
        #pragma unroll
        for (int s = 0; s < 16; ++s) {
            double m2 = __dmul_rn(mi_d, (double)mf[s]);
            Dk[s] = __dadd_rn(Dk[s],
                    __dmul_rn(__dmul_rn(2.0, __dsub_rn(1.0, m2)), lm));
        }
    }

    ull key[16];
    #pragma unroll
    for (int s = 0; s < 16; ++s)
        key[s] = (((ull)__double_as_longlong(Dk[s])) & ~1023ull)
               | (unsigned)(s*64 + lane);

    for (int k = 0; k < KQ; ++k) {
        ull a0 = umin64(key[0],  key[1]),  a1 = umin64(key[2],  key[3]);
        ull a2 = umin64(key[4],  key[5]),  a3 = umin64(key[6],  key[7]);
        ull a4 = umin64(key[8],  key[9]),  a5 = umin64(key[10], key[11]);
        ull a6 = umin64(key[12], key[13]), a7 = umin64(key[14], key[15]);
        ull b0 = umin64(a0, a1), b1 = umin64(a2, a3);
        ull b2 = umin64(a4, a5), b3 = umin64(a6, a7);
        ull bk = umin64(umin64(b0, b1), umin64(b2, b3));
        #pragma unroll
        for (int off = 32; off; off >>= 1)
            bk = umin64(bk, (ull)__shfl_xor(bk, off));
        int j = (int)(bk & 1023ull);
        if (lane == 0) {
            int rg = row*KQ + k;
            idx_ws[rg] = j;
            out[EIDX_OFF + rg] = (float)j;
        }
        bool mine = ((j & 63) == lane);
        int s_win = j >> 6;
        #pragma unroll
        for (int s = 0; s < 16; ++s)
            key[s] = (mine && s == s_win) ? ~0ull : key[s];
    }
}

// ---------------------------------------------------------------------------
// Kernel B v14 = v13 + the two fixes the counters demanded:
//  (1) __launch_bounds__(512,4): VGPR cap 128. v13's allocator chose 52 VGPR
//      (chasing occupancy the 47.6KB LDS already caps at 2-3 blocks/CU) and
//      SANK the 8 b1 global loads to their uses -> 8 serial L2 round-trips
//      per chunk. 128-VGPR budget removes the pressure.
//  (2) b1 prefetched ONE CHUNK AHEAD (unroll-2, static banks b1A/b1B): loads
//      issue at chunk top, the bottom __syncthreads' vmcnt(0) drain completes
//      them, use is a full chunk (~1900cy) later. Loads cannot be sunk past
//      a barrier -> serialization structurally impossible.
// Everything else identical to v13 (passed absmax 0.043): b0 k-half via LDS
// dbuf + paired-row XOR swizzle, b1 k-half direct from XCD-L2-resident wpad.
// ---------------------------------------------------------------------------
struct FusedSmem {
    alignas(16) unsigned short atoms[256*56];  // 28672 B (scaled+poisoned f16)
    alignas(16) unsigned short Bl[2*4096];     // 16384 B: dbuf k-half chunk
    alignas(16) float drow[MTILE];             // 512
    int residg[256];                           // 1024
    float gsh[EFQ], bsh[EFQ];                  // 1024
};                                             // 47,616 B

// RBF features [8] for one (center-atom, neighbor-atom) pair, rbase folded
// into rboff. Poisoned coords (+/-30000) make all eight exp2 give exact +0.
static __device__ __forceinline__ void gen_rbf(
    const char* __restrict__ rowA, const char* __restrict__ rowB,
    int ao, int bo, float rboff, uint32_t* __restrict__ v)
{
    uint2 ca = *reinterpret_cast<const uint2*>(rowA + ao);
    uint2 nb = *reinterpret_cast<const uint2*>(rowB + bo);
    half2t c0 = __builtin_bit_cast(half2t, ca.x);
    half2t c1 = __builtin_bit_cast(half2t, ca.y);
    half2t n0 = __builtin_bit_cast(half2t, nb.x);
    half2t n1 = __builtin_bit_cast(half2t, nb.y);
    half2t dxy = c0 - n0;                        // v_pk_add_f16
    half2t dzw = c1 - n1;
    float dx = (float)dxy[0], dy = (float)dxy[1], dz = (float)dzw[0];
    float ssq = __fmaf_rn(dx, dx, __fmaf_rn(dy, dy,
                __fmaf_rn(dz, dz, 9.2332585e-7f)));     // (1e-6 scaled)
    float u = __builtin_amdgcn_sqrtf(ssq) + rboff;
    const float CJ[8] = {0.0f, 1.28119795f, 2.5623959f, 3.84359385f,
                         5.1247918f, 6.40598975f, 7.6871877f, 8.96838565f};
    #pragma unroll
    for (int k = 0; k < 4; ++k) {
        float t0 = u - CJ[2*k];
        float t1 = u - CJ[2*k+1];
        v[k] = pkh(__builtin_amdgcn_exp2f(-(t0*t0)),
                   __builtin_amdgcn_exp2f(-(t1*t1)));
    }
}

__global__ __launch_bounds__(512, 4) void fused_kernel(
    const float* __restrict__ X, const float* __restrict__ atom_mask,
    const _Float16* __restrict__ wpad, const float* __restrict__ gamma,
    const float* __restrict__ beta, const int* __restrict__ idx_ws,
    float* __restrict__ out)
{
    __shared__ FusedSmem sm;
    const int t = threadIdx.x;               // 0..511
    const int row0 = blockIdx.x * MTILE;
    const int b = row0 / (LQ*KQ);            // tiles never straddle b (30720 % 128 == 0)

    if (t < MTILE) {
        int rg = row0 + t;
        int rem = rg - b*(LQ*KQ);
        int i = rem / KQ;
        int j = idx_ws[rg];
        sm.residg[t]       = b*LQ + i;
        sm.residg[MTILE+t] = b*LQ + j;
        sm.drow[t] = (float)j - (float)i;
    }
    if (t < EFQ) { sm.gsh[t] = gamma[t]; sm.bsh[t] = beta[t]; }
    __syncthreads();

    const int w = t >> 6, lane = t & 63, q = lane >> 4, l15 = lane & 15;
    const int m = w*16 + l15;                 // tile-local row (0..127)

    // ---- B LDS staging: k-half 0..31, one 16B unit per thread ------------
    // Physical: 64 rows x 128B, linear dst (r = t>>3, slot = t&7).
    // Logical (n, kslot) at slot ((n&1)*4 + kslot) ^ (r&7), n = 2r + hi.
    // Source pre-swizzled so linear dst receives the right data.
    const int scomb = (t & 7) ^ ((t >> 3) & 7);
    const int sn    = (((t >> 3)) << 1) | (scomb >> 2);
    const _Float16* stSrc = wpad + (size_t)sn*KPAD + (scomb & 3)*8;
    auto stage = [&](int c) {
        __builtin_amdgcn_global_load_lds(
            (const __attribute__((address_space(1))) uint32_t*)(stSrc + c*64),
            (__attribute__((address_space(3))) uint32_t*)
                &sm.Bl[((c & 1) << 12) + (t << 3)],
            16, 0, 0);
    };
    stage(0);                                 // flies across the prologue

    // stage atoms: fp32 global -> packed f16 LDS (raw, x,y,z,0 per slot)
    for (int u2 = t; u2 < 256*14; u2 += 512) {   // 7 exact iterations
        int s = u2 / 14; int a = u2 - s*14;
        const float* xp = X + (size_t)sm.residg[s]*42 + a*3;
        uint2 pk; pk.x = pkh(xp[0], xp[1]); pk.y = pkh(xp[2], 0.0f);
        *reinterpret_cast<uint2*>(&sm.atoms[s*56 + a*4]) = pk;
    }
    __syncthreads();

    if (t < 256) {   // Cb (raw) into slot 4, then scale + mask-poison all 14
        unsigned short* at = &sm.atoms[t*56];
        auto ld3 = [&](int slot, float& x, float& y, float& z) {
            half2t p0 = *reinterpret_cast<const half2t*>(at + slot*4);
            half2t p1 = *reinterpret_cast<const half2t*>(at + slot*4 + 2);
            x = (float)p0[0]; y = (float)p0[1]; z = (float)p1[0];
        };
        float Nx,Ny,Nz, Cax,Cay,Caz, Cx,Cy,Cz;
        ld3(0, Nx,Ny,Nz); ld3(1, Cax,Cay,Caz); ld3(2, Cx,Cy,Cz);
        float bx=Cax-Nx, by=Cay-Ny, bz=Caz-Nz;
        float ex=Cx-Cax, ey=Cy-Cay, ez=Cz-Caz;
        float ax = by*ez - bz*ey, ay = bz*ex - bx*ez, az = bx*ey - by*ex;
        float cbx = -0.58273431f*ax + 0.56802827f*bx - 0.54067466f*ex + Cax;
        float cby = -0.58273431f*ay + 0.56802827f*by - 0.54067466f*ey + Cay;
        float cbz = -0.58273431f*az + 0.56802827f*bz - 0.54067466f*ez + Caz;
        uint2 pk4; pk4.x = pkh(cbx, cby); pk4.y = pkh(cbz, 0.0f);
        *reinterpret_cast<uint2*>(at + 4*4) = pk4;   // slot 4 = Cb (raw)

        const float P = (t < MTILE) ? 30000.0f : -30000.0f;  // center/neighbor
        const uint32_t pxx = pkh(P, P), pxy = pkh(P, 0.0f);
        half2t sc2; sc2[0] = (_Float16)0.96089846f; sc2[1] = (_Float16)0.96089846f;
        const float* amp = &atom_mask[(size_t)sm.residg[t]*AQ];
        #pragma unroll
        for (int a = 0; a < AQ; ++a) {
            uint2 vv = *reinterpret_cast<const uint2*>(at + a*4);
            half2t lo = __builtin_bit_cast(half2t, vv.x) * sc2;
            half2t hi = __builtin_bit_cast(half2t, vv.y) * sc2;
            bool msk = amp[a] > 0.5f;
            uint2 ov;
            ov.x = msk ? pxx : __builtin_bit_cast(uint32_t, lo);
            ov.y = msk ? pxy : __builtin_bit_cast(uint32_t, hi);
            *reinterpret_cast<uint2*>(at + a*4) = ov;
        }
    }

    // ---- b0 LDS read base: (n = nt*16+l15, kslot q) -> shorts offset
    const int bbase = (l15 >> 1)*64 + ((((((l15 & 1) << 2) | q)) ^ (l15 >> 1)) << 3);

    // ---- b1 direct-L2 base: n = nt*16 + l15, k = 32 + q*8
    const _Float16* bg = wpad + (size_t)l15*KPAD + 32 + q*8;

    const char* rowA = (const char*)&sm.atoms[m*56];
    const char* rowB = (const char*)&sm.atoms[(MTILE+m)*56];
    const int   qlt2  = (q < 2) ? 1 : 0;
    const float rboff = -(float)((q & 1) * 8) * 1.28119795f;

    floatx4 acc[8];
    #pragma unroll
    for (int nt = 0; nt < 8; ++nt) acc[nt] = (floatx4){0.f,0.f,0.f,0.f};

    half8 b1A[8], b1B[8];
    #pragma unroll
    for (int nt = 0; nt < 8; ++nt)            // prefetch b1 for chunk 0
        b1A[nt] = *reinterpret_cast<const half8*>(bg + (size_t)nt*(16*KPAD));

    __syncthreads();   // atoms visible; stage(0) + b1A drained (vmcnt 0)

    union H8 { uint32_t u[4]; half8 h; };
    auto chunk = [&](int c, half8 (&cur)[8], half8 (&nxt)[8]) {
        if (c < NCHUNK-1) {
            stage(c+1);                       // dbuf DMA, drained by bottom barrier
            #pragma unroll
            for (int nt = 0; nt < 8; ++nt)    // prefetch next chunk's b1 (L2);
                nxt[nt] = *reinterpret_cast<const half8*>(
                    bg + (size_t)nt*(16*KPAD) + (c+1)*64);
        }

        // pair addressing: p0 = 4c - (q<2), p1 = p0 + 2; a = p/14, bp = p%14
        int p0 = 4*c - qlt2;
        int p1 = p0 + 2;
        int pa0 = (p0 * 74899) >> 20;  int pa1 = (p1 * 74899) >> 20;
        pa0 = pa0 > 13 ? 13 : pa0;     pa1 = pa1 > 13 ? 13 : pa1;
        int ao0 = pa0 << 3, bo0 = (p0 - pa0*14) << 3;
        int ao1 = pa1 << 3, bo1 = (p1 - pa1*14) << 3;

        H8 a00, a01;
        if (c == 0 && qlt2) {                 // positional features (f0 = 0 or 8)
            const float fr[8] = {1.0f, 0.31622776601683794f, 0.1f,
                0.031622776601683794f, 0.01f, 0.0031622776601683794f,
                0.001f, 0.00031622776601683794f};
            float dr = sm.drow[m];
            float e[8];
            if (q == 0) {
                #pragma unroll
                for (int j = 0; j < 8; ++j) e[j] = __cosf(dr * fr[j]);
            } else {
                #pragma unroll
                for (int j = 0; j < 8; ++j) e[j] = __sinf(dr * fr[j]);
            }
            #pragma unroll
            for (int k = 0; k < 4; ++k) a00.u[k] = pkh(e[2*k], e[2*k+1]);
        } else {
            gen_rbf(rowA, rowB, ao0, bo0, rboff, a00.u);
        }
        gen_rbf(rowA, rowB, ao1, bo1, rboff, a01.u);

        const unsigned short* Bb = &sm.Bl[(c & 1) << 12];
        #pragma unroll
        for (int nt = 0; nt < 8; ++nt) {       // pass 1: k 0..31 from LDS
            half8 b0 = *reinterpret_cast<const half8*>(&Bb[nt*512 + bbase]);
            acc[nt] = __builtin_amdgcn_mfma_f32_16x16x32_f16(a00.h, b0, acc[nt], 0, 0, 0);
        }
        #pragma unroll
        for (int nt = 0; nt < 8; ++nt)         // pass 2: k 32..63 from regs
            acc[nt] = __builtin_amdgcn_mfma_f32_16x16x32_f16(a01.h, cur[nt], acc[nt], 0, 0, 0);

        __syncthreads();   // drains stage DMA + b1 prefetch; fences Bl reads
    };

    for (int c = 0; c < NCHUNK; c += 2) {      // NCHUNK = 50 (even)
        chunk(c,     b1A, b1B);
        chunk(c + 1, b1B, b1A);
    }

    // LayerNorm epilogue. C/D layout: col = lane&15, row = quad*4 + reg.
    #pragma unroll
    for (int v = 0; v < 4; ++v) {
        float s = 0.f, s2 = 0.f;
        #pragma unroll
        for (int nt = 0; nt < 8; ++nt) { float x = acc[nt][v]; s += x; s2 += x*x; }
        #pragma unroll
        for (int off = 1; off < 16; off <<= 1) {
            s  += __shfl_xor(s,  off);
            s2 += __shfl_xor(s2, off);
        }
        float mean = s * (1.0f/128.0f);
        float var  = s2 * (1.0f/128.0f) - mean*mean;
        float rstd = 1.0f / sqrtf(var + 1e-5f);
        int row_l = w*16 + q*4 + v;
        size_t obase = (size_t)(row0 + row_l)*EFQ;
        #pragma unroll
        for (int nt = 0; nt < 8; ++nt) {
            int col = nt*16 + l15;
            out[obase + col] = (acc[nt][v] - mean)*rstd*sm.gsh[col] + sm.bsh[col];
        }
    }
}

extern "C" void kernel_launch(void* const* d_in, const int* in_sizes, int n_in,
                              void* d_out, int out_size, void* d_ws, size_t ws_size,
                              hipStream_t stream)
{
    const float* X         = (const float*)d_in[0];
    const float* mask      = (const float*)d_in[1];
    // d_in[2] residue_idx, d_in[3] chain_labels: unused by the reference math
    const float* atom_mask = (const float*)d_in[4];
    const float* W         = (const float*)d_in[5];
    const float* gamma     = (const float*)d_in[6];
    const float* beta      = (const float*)d_in[7];
    float* out = (float*)d_out;

    int*       idx_ws = (int*)d_ws;                               // 61440*4 B
    _Float16*  wpad   = (_Float16*)((char*)d_ws + 262144);        // 128*3200*2 B

    hipLaunchKernelGGL(topk_kernel, dim3(306), dim3(512), 0, stream,
                       X, mask, W, out, idx_ws, wpad);
    hipLaunchKernelGGL(fused_kernel, dim3(ROWS/MTILE), dim3(512), 0, stream,
                       X, atom_mask, wpad, gamma, beta, idx_ws, out);
}

// Round 8
// 180.558 us; speedup vs baseline: 1.7031x; 1.7031x over previous
//
#include <hip/hip_runtime.h>
#include <hip/hip_bf16.h>
#include <stdint.h>

#define LQ 1024
#define BQ 2
#define AQ 14
#define KQ 30
#define EFQ 128
#define EDGE_IN 3152
#define KPAD 3200
#define NCHUNK 50
#define MTILE 128
#define ROWS (BQ*LQ*KQ)            /* 61440 */
#define EIDX_OFF (ROWS*EFQ)        /* 7864320 */

typedef __attribute__((ext_vector_type(8))) _Float16 half8;
typedef __attribute__((ext_vector_type(2))) _Float16 half2t;
typedef __attribute__((ext_vector_type(4))) float floatx4;
typedef unsigned long long ull;

static __device__ __forceinline__ uint32_t pkh(float a, float b) {
    auto h = __builtin_amdgcn_cvt_pkrtz(a, b);   // __fp16 ext_vector(2)
    return __builtin_bit_cast(uint32_t, h);
}
static __device__ __forceinline__ ull umin64(ull a, ull b) { return a < b ? a : b; }

// ---------------------------------------------------------------------------
// Kernel A v6 (unchanged): blocks 0..255 topk (8 rows/block, one wave per row,
// u64-packed keys); blocks 256..305: W fp32 -> f16 padded copy.
// ---------------------------------------------------------------------------
__global__ __launch_bounds__(512) void topk_kernel(
    const float* __restrict__ X, const float* __restrict__ mask,
    const float* __restrict__ W, float* __restrict__ out,
    int* __restrict__ idx_ws, _Float16* __restrict__ wpad)
{
    __shared__ float xs[LQ], ys[LQ], zs[LQ], ms[LQ];
    const int t = threadIdx.x;

    if (blockIdx.x >= 256) {                    // ---- merged wpad ----
        int base = (blockIdx.x - 256)*8192 + t; // 50 blocks x 8192 = 409600 exact
        #pragma unroll
        for (int r = 0; r < 16; ++r) {
            int idx = base + r*512;
            int n = idx / KPAD, f = idx - n*KPAD;
            float v = (f < EDGE_IN) ? W[(size_t)n*EDGE_IN + f] : 0.0f;
            wpad[idx] = (_Float16)v;
        }
        return;
    }

    const int w = t >> 6, lane = t & 63;
    const int row = blockIdx.x*8 + w;           // same b for whole block
    const int b = row >> 10, i = row & (LQ - 1);

    for (int j = t; j < LQ; j += 512) {
        size_t base = ((size_t)(b*LQ + j))*42 + 3;   // atom 1 (CA)
        xs[j] = X[base+0]; ys[j] = X[base+1]; zs[j] = X[base+2];
        ms[j] = mask[b*LQ + j];
    }
    __syncthreads();

    const float mif = ms[i];
    const double cx = (double)xs[i], cy = (double)ys[i], cz = (double)zs[i];

    double Dk[16]; float mf[16];
    bool allone = (mif == 1.0f);
    #pragma unroll
    for (int s = 0; s < 16; ++s) {
        int j = s*64 + lane;
        double dx = __dsub_rn(cx, (double)xs[j]);
        double dy = __dsub_rn(cy, (double)ys[j]);
        double dz = __dsub_rn(cz, (double)zs[j]);
        mf[s] = ms[j];
        Dk[s] = __dadd_rn(__dadd_rn(__dmul_rn(dx,dx), __dmul_rn(dy,dy)),
                          __dmul_rn(dz,dz));
        allone = allone && (mf[s] == 1.0f);
    }

    if (!__all(allone ? 1 : 0)) {
        // exact general path: D = mi*mj*sqrt(ssq+1e-6); key = D + 2(1-m2)*max(D)
        const double mi_d = (double)mif;
        double lm = 0.0;
        #pragma unroll
        for (int s = 0; s < 16; ++s) {
            double m2 = __dmul_rn(mi_d, (double)mf[s]);
            Dk[s] = __dmul_rn(m2, sqrt(__dadd_rn(Dk[s], 1e-6)));
            lm = fmax(lm, Dk[s]);
        }
        #pragma unroll
        for (int off = 32; off; off >>= 1) lm = fmax(lm, __shfl_xor(lm, off));
        #pragma unroll
        for (int s = 0; s < 16; ++s) {
            double m2 = __dmul_rn(mi_d, (double)mf[s]);
            Dk[s] = __dadd_rn(Dk[s],
                    __dmul_rn(__dmul_rn(2.0, __dsub_rn(1.0, m2)), lm));
        }
    }

    ull key[16];
    #pragma unroll
    for (int s = 0; s < 16; ++s)
        key[s] = (((ull)__double_as_longlong(Dk[s])) & ~1023ull)
               | (unsigned)(s*64 + lane);

    for (int k = 0; k < KQ; ++k) {
        ull a0 = umin64(key[0],  key[1]),  a1 = umin64(key[2],  key[3]);
        ull a2 = umin64(key[4],  key[5]),  a3 = umin64(key[6],  key[7]);
        ull a4 = umin64(key[8],  key[9]),  a5 = umin64(key[10], key[11]);
        ull a6 = umin64(key[12], key[13]), a7 = umin64(key[14], key[15]);
        ull b0 = umin64(a0, a1), b1 = umin64(a2, a3);
        ull b2 = umin64(a4, a5), b3 = umin64(a6, a7);
        ull bk = umin64(umin64(b0, b1), umin64(b2, b3));
        #pragma unroll
        for (int off = 32; off; off >>= 1)
            bk = umin64(bk, (ull)__shfl_xor(bk, off));
        int j = (int)(bk & 1023ull);
        if (lane == 0) {
            int rg = row*KQ + k;
            idx_ws[rg] = j;
            out[EIDX_OFF + rg] = (float)j;
        }
        bool mine = ((j & 63) == lane);
        int s_win = j >> 6;
        #pragma unroll
        for (int s = 0; s < 16; ++s)
            key[s] = (mine && s == s_win) ? ~0ull : key[s];
    }
}

// ---------------------------------------------------------------------------
// Kernel B v15 = v12 gen/poison/swizzle + 4-wave/32-row geometry.
// Model: v12's LDS pipe is ~93% busy; 80% of that is B-reads, redundant 8x
// (every wave reads the whole W chunk). 4 waves x 32 rows x 128 cols halves
// B-reads per row served (64 b128/chunk-block), keeps gen at exactly one
// gen_rbf per feature (4/thread, no duplication), v7 2-barrier skeleton,
// v7 swizzle byte-identical. This is v8's geometry retested with its three
// confounds removed (heavy masked gen8, 3M bank conflicts, VGPR squeeze).
// LDS 49.4 KB -> 3 blocks/CU (12 waves/CU). Direct-L2 B: abandoned (v9/13/14).
// ---------------------------------------------------------------------------
struct FusedSmem {
    alignas(16) unsigned short atoms[256*56];  // 28672 B (scaled+poisoned f16)
    alignas(16) unsigned short Bl[8192];       // 16384 B: W chunk, v7 XOR swizzle
    alignas(16) float drow[MTILE];             // 512
    int residg[256];                           // 1024
    float gsh[EFQ], bsh[EFQ];                  // 1024
};                                             // 47,616 B

// RBF features [8] for one (center-atom, neighbor-atom) pair, rbase folded
// into rboff. Poisoned coords (+/-30000) make all eight exp2 give exact +0.
static __device__ __forceinline__ void gen_rbf(
    const char* __restrict__ rowA, const char* __restrict__ rowB,
    int ao, int bo, float rboff, uint32_t* __restrict__ v)
{
    uint2 ca = *reinterpret_cast<const uint2*>(rowA + ao);
    uint2 nb = *reinterpret_cast<const uint2*>(rowB + bo);
    half2t c0 = __builtin_bit_cast(half2t, ca.x);
    half2t c1 = __builtin_bit_cast(half2t, ca.y);
    half2t n0 = __builtin_bit_cast(half2t, nb.x);
    half2t n1 = __builtin_bit_cast(half2t, nb.y);
    half2t dxy = c0 - n0;                        // v_pk_add_f16
    half2t dzw = c1 - n1;
    float dx = (float)dxy[0], dy = (float)dxy[1], dz = (float)dzw[0];
    float ssq = __fmaf_rn(dx, dx, __fmaf_rn(dy, dy,
                __fmaf_rn(dz, dz, 9.2332585e-7f)));     // (1e-6 scaled)
    float u = __builtin_amdgcn_sqrtf(ssq) + rboff;
    const float CJ[8] = {0.0f, 1.28119795f, 2.5623959f, 3.84359385f,
                         5.1247918f, 6.40598975f, 7.6871877f, 8.96838565f};
    #pragma unroll
    for (int k = 0; k < 4; ++k) {
        float t0 = u - CJ[2*k];
        float t1 = u - CJ[2*k+1];
        v[k] = pkh(__builtin_amdgcn_exp2f(-(t0*t0)),
                   __builtin_amdgcn_exp2f(-(t1*t1)));
    }
}

__global__ __launch_bounds__(256, 4) void fused_kernel(
    const float* __restrict__ X, const float* __restrict__ atom_mask,
    const _Float16* __restrict__ wpad, const float* __restrict__ gamma,
    const float* __restrict__ beta, const int* __restrict__ idx_ws,
    float* __restrict__ out)
{
    __shared__ FusedSmem sm;
    const int t = threadIdx.x;               // 0..255
    const int row0 = blockIdx.x * MTILE;
    const int b = row0 / (LQ*KQ);            // tiles never straddle b (30720 % 128 == 0)

    if (t < MTILE) {
        int rg = row0 + t;
        int rem = rg - b*(LQ*KQ);
        int i = rem / KQ;
        int j = idx_ws[rg];
        sm.residg[t]       = b*LQ + i;
        sm.residg[MTILE+t] = b*LQ + j;
        sm.drow[t] = (float)j - (float)i;
    }
    if (t < EFQ) { sm.gsh[t] = gamma[t]; sm.bsh[t] = beta[t]; }
    __syncthreads();

    const int w = t >> 6, lane = t & 63, q = lane >> 4, l15 = lane & 15;
    const int m0 = w*32 + l15, m1 = m0 + 16; // the wave's two 16-row groups

    // ---- staging hoists (v7 math; 4 regions/thread at 256 threads) -------
    int stRegion[4]; const _Float16* stBase[4];
    #pragma unroll
    for (int i2 = 0; i2 < 4; ++i2) {
        int region = w*4 + i2;                        // 16 regions x 8 rows
        int n = region*8 + (lane >> 3);
        int kbsrc = (lane & 7) ^ (lane >> 3);
        stRegion[i2] = region;
        stBase[i2] = wpad + (size_t)n*KPAD + kbsrc*8;
    }
    auto stage = [&](int c) {
        #pragma unroll
        for (int i2 = 0; i2 < 4; ++i2) {
            const _Float16* g = stBase[i2] + c*64;
            __builtin_amdgcn_global_load_lds(
                (const __attribute__((address_space(1))) uint32_t*)g,
                (__attribute__((address_space(3))) uint32_t*)&sm.Bl[stRegion[i2]*512],
                16, 0, 0);
        }
    };

    // stage atoms: fp32 global -> packed f16 LDS (raw, x,y,z,0 per slot)
    for (int u2 = t; u2 < 256*14; u2 += 256) {   // 14 exact iterations
        int s = u2 / 14; int a = u2 - s*14;
        const float* xp = X + (size_t)sm.residg[s]*42 + a*3;
        uint2 pk; pk.x = pkh(xp[0], xp[1]); pk.y = pkh(xp[2], 0.0f);
        *reinterpret_cast<uint2*>(&sm.atoms[s*56 + a*4]) = pk;
    }
    __syncthreads();

    {   // all 256 threads: Cb (raw) into slot 4, then scale + mask-poison
        unsigned short* at = &sm.atoms[t*56];
        auto ld3 = [&](int slot, float& x, float& y, float& z) {
            half2t p0 = *reinterpret_cast<const half2t*>(at + slot*4);
            half2t p1 = *reinterpret_cast<const half2t*>(at + slot*4 + 2);
            x = (float)p0[0]; y = (float)p0[1]; z = (float)p1[0];
        };
        float Nx,Ny,Nz, Cax,Cay,Caz, Cx,Cy,Cz;
        ld3(0, Nx,Ny,Nz); ld3(1, Cax,Cay,Caz); ld3(2, Cx,Cy,Cz);
        float bx=Cax-Nx, by=Cay-Ny, bz=Caz-Nz;
        float ex=Cx-Cax, ey=Cy-Cay, ez=Cz-Caz;
        float ax = by*ez - bz*ey, ay = bz*ex - bx*ez, az = bx*ey - by*ex;
        float cbx = -0.58273431f*ax + 0.56802827f*bx - 0.54067466f*ex + Cax;
        float cby = -0.58273431f*ay + 0.56802827f*by - 0.54067466f*ey + Cay;
        float cbz = -0.58273431f*az + 0.56802827f*bz - 0.54067466f*ez + Caz;
        uint2 pk4; pk4.x = pkh(cbx, cby); pk4.y = pkh(cbz, 0.0f);
        *reinterpret_cast<uint2*>(at + 4*4) = pk4;   // slot 4 = Cb (raw)

        const float P = (t < MTILE) ? 30000.0f : -30000.0f;  // center/neighbor
        const uint32_t pxx = pkh(P, P), pxy = pkh(P, 0.0f);
        half2t sc2; sc2[0] = (_Float16)0.96089846f; sc2[1] = (_Float16)0.96089846f;
        const float* amp = &atom_mask[(size_t)sm.residg[t]*AQ];
        #pragma unroll
        for (int a = 0; a < AQ; ++a) {
            uint2 vv = *reinterpret_cast<const uint2*>(at + a*4);
            half2t lo = __builtin_bit_cast(half2t, vv.x) * sc2;
            half2t hi = __builtin_bit_cast(half2t, vv.y) * sc2;
            bool msk = amp[a] > 0.5f;
            uint2 ov;
            ov.x = msk ? pxx : __builtin_bit_cast(uint32_t, lo);
            ov.y = msk ? pxy : __builtin_bit_cast(uint32_t, hi);
            *reinterpret_cast<uint2*>(at + a*4) = ov;
        }
    }

    // ---- B-read LDS offsets (v7 swizzle, byte-identical) -----------------
    int boff0[8], boff1[8];
    #pragma unroll
    for (int nt = 0; nt < 8; ++nt) {
        int n = nt*16 + l15;
        boff0[nt] = n*64 + ((q ^ (n&7))*8);
        boff1[nt] = n*64 + (((4+q) ^ (n&7))*8);
    }

    const char* rowA0 = (const char*)&sm.atoms[m0*56];
    const char* rowB0 = (const char*)&sm.atoms[(MTILE+m0)*56];
    const char* rowA1 = (const char*)&sm.atoms[m1*56];
    const char* rowB1 = (const char*)&sm.atoms[(MTILE+m1)*56];
    const int   qlt2  = (q < 2) ? 1 : 0;
    const float rboff = -(float)((q & 1) * 8) * 1.28119795f;

    floatx4 acc0[8], acc1[8];
    #pragma unroll
    for (int nt = 0; nt < 8; ++nt) {
        acc0[nt] = (floatx4){0.f,0.f,0.f,0.f};
        acc1[nt] = (floatx4){0.f,0.f,0.f,0.f};
    }

    __syncthreads();   // atoms scaled/poisoned visible to all waves

    union H8 { uint32_t u[4]; half8 h; };
    for (int c = 0; c < NCHUNK; ++c) {
        if (c) __syncthreads();               // all reads of previous chunk done
        stage(c);                             // async DMA, in flight during gen

        // pair addressing: p0 = 4c - (q<2), p1 = p0 + 2; a = p/14, bp = p%14
        int p0 = 4*c - qlt2;
        int p1 = p0 + 2;
        int pa0 = (p0 * 74899) >> 20;  int pa1 = (p1 * 74899) >> 20;
        pa0 = pa0 > 13 ? 13 : pa0;     pa1 = pa1 > 13 ? 13 : pa1;
        int ao0 = pa0 << 3, bo0 = (p0 - pa0*14) << 3;
        int ao1 = pa1 << 3, bo1 = (p1 - pa1*14) << 3;

        H8 a00, a01, a10, a11;
        if (c == 0 && qlt2) {                 // positional features (f0 = 0 or 8)
            const float fr[8] = {1.0f, 0.31622776601683794f, 0.1f,
                0.031622776601683794f, 0.01f, 0.0031622776601683794f,
                0.001f, 0.00031622776601683794f};
            float dr0 = sm.drow[m0], dr1 = sm.drow[m1];
            float e0[8], e1[8];
            if (q == 0) {
                #pragma unroll
                for (int j = 0; j < 8; ++j) { e0[j] = __cosf(dr0 * fr[j]); e1[j] = __cosf(dr1 * fr[j]); }
            } else {
                #pragma unroll
                for (int j = 0; j < 8; ++j) { e0[j] = __sinf(dr0 * fr[j]); e1[j] = __sinf(dr1 * fr[j]); }
            }
            #pragma unroll
            for (int k = 0; k < 4; ++k) {
                a00.u[k] = pkh(e0[2*k], e0[2*k+1]);
                a10.u[k] = pkh(e1[2*k], e1[2*k+1]);
            }
        } else {
            gen_rbf(rowA0, rowB0, ao0, bo0, rboff, a00.u);
            gen_rbf(rowA1, rowB1, ao0, bo0, rboff, a10.u);
        }
        gen_rbf(rowA0, rowB0, ao1, bo1, rboff, a01.u);
        gen_rbf(rowA1, rowB1, ao1, bo1, rboff, a11.u);

        __syncthreads();                      // drains DMA (vmcnt 0): Bl ready
        #pragma unroll
        for (int nt = 0; nt < 8; ++nt) {
            half8 b0 = *reinterpret_cast<const half8*>(&sm.Bl[boff0[nt]]);
            half8 b1 = *reinterpret_cast<const half8*>(&sm.Bl[boff1[nt]]);
            acc0[nt] = __builtin_amdgcn_mfma_f32_16x16x32_f16(a00.h, b0, acc0[nt], 0, 0, 0);
            acc0[nt] = __builtin_amdgcn_mfma_f32_16x16x32_f16(a01.h, b1, acc0[nt], 0, 0, 0);
            acc1[nt] = __builtin_amdgcn_mfma_f32_16x16x32_f16(a10.h, b0, acc1[nt], 0, 0, 0);
            acc1[nt] = __builtin_amdgcn_mfma_f32_16x16x32_f16(a11.h, b1, acc1[nt], 0, 0, 0);
        }
    }

    // LayerNorm epilogue. C/D layout: col = lane&15, row = quad*4 + reg.
    auto lnrows = [&](const floatx4* acc, int g) {
        #pragma unroll
        for (int v = 0; v < 4; ++v) {
            float s = 0.f, s2 = 0.f;
            #pragma unroll
            for (int nt = 0; nt < 8; ++nt) { float x = acc[nt][v]; s += x; s2 += x*x; }
            #pragma unroll
            for (int off = 1; off < 16; off <<= 1) {
                s  += __shfl_xor(s,  off);
                s2 += __shfl_xor(s2, off);
            }
            float mean = s * (1.0f/128.0f);
            float var  = s2 * (1.0f/128.0f) - mean*mean;
            float rstd = 1.0f / sqrtf(var + 1e-5f);
            int row_l = w*32 + g*16 + q*4 + v;
            size_t obase = (size_t)(row0 + row_l)*EFQ;
            #pragma unroll
            for (int nt = 0; nt < 8; ++nt) {
                int col = nt*16 + l15;
                out[obase + col] = (acc[nt][v] - mean)*rstd*sm.gsh[col] + sm.bsh[col];
            }
        }
    };
    lnrows(acc0, 0);
    lnrows(acc1, 1);
}

extern "C" void kernel_launch(void* const* d_in, const int* in_sizes, int n_in,
                              void* d_out, int out_size, void* d_ws, size_t ws_size,
                              hipStream_t stream)
{
    const float* X         = (const float*)d_in[0];
    const float* mask      = (const float*)d_in[1];
    // d_in[2] residue_idx, d_in[3] chain_labels: unused by the reference math
    const float* atom_mask = (const float*)d_in[4];
    const float* W         = (const float*)d_in[5];
    const float* gamma     = (const float*)d_in[6];
    const float* beta      = (const float*)d_in[7];
    float* out = (float*)d_out;

    int*       idx_ws = (int*)d_ws;                               // 61440*4 B
    _Float16*  wpad   = (_Float16*)((char*)d_ws + 262144);        // 128*3200*2 B

    hipLaunchKernelGGL(topk_kernel, dim3(306), dim3(512), 0, stream,
                       X, mask, W, out, idx_ws, wpad);
    hipLaunchKernelGGL(fused_kernel, dim3(ROWS/MTILE), dim3(256), 0, stream,
                       X, atom_mask, wpad, gamma, beta, idx_ws, out);
}

// Round 9
// 173.870 us; speedup vs baseline: 1.7686x; 1.0385x over previous
//
#include <hip/hip_runtime.h>
#include <hip/hip_bf16.h>
#include <stdint.h>

#define LQ 1024
#define BQ 2
#define AQ 14
#define KQ 30
#define EFQ 128
#define EDGE_IN 3152
#define KPAD 3200
#define NCHUNK 50
#define MTILE 128
#define ROWS (BQ*LQ*KQ)            /* 61440 */
#define EIDX_OFF (ROWS*EFQ)        /* 7864320 */

typedef __attribute__((ext_vector_type(8))) _Float16 half8;
typedef __attribute__((ext_vector_type(2))) _Float16 half2t;
typedef __attribute__((ext_vector_type(4))) float floatx4;
typedef unsigned long long ull;

static __device__ __forceinline__ uint32_t pkh(float a, float b) {
    auto h = __builtin_amdgcn_cvt_pkrtz(a, b);   // __fp16 ext_vector(2)
    return __builtin_bit_cast(uint32_t, h);
}
static __device__ __forceinline__ ull umin64(ull a, ull b) { return a < b ? a : b; }

// ---------------------------------------------------------------------------
// Kernel A v6 (unchanged): blocks 0..255 topk (8 rows/block, one wave per row,
// u64-packed keys); blocks 256..305: W fp32 -> f16 padded copy.
// ---------------------------------------------------------------------------
__global__ __launch_bounds__(512) void topk_kernel(
    const float* __restrict__ X, const float* __restrict__ mask,
    const float* __restrict__ W, float* __restrict__ out,
    int* __restrict__ idx_ws, _Float16* __restrict__ wpad)
{
    __shared__ float xs[LQ], ys[LQ], zs[LQ], ms[LQ];
    const int t = threadIdx.x;

    if (blockIdx.x >= 256) {                    // ---- merged wpad ----
        int base = (blockIdx.x - 256)*8192 + t; // 50 blocks x 8192 = 409600 exact
        #pragma unroll
        for (int r = 0; r < 16; ++r) {
            int idx = base + r*512;
            int n = idx / KPAD, f = idx - n*KPAD;
            float v = (f < EDGE_IN) ? W[(size_t)n*EDGE_IN + f] : 0.0f;
            wpad[idx] = (_Float16)v;
        }
        return;
    }

    const int w = t >> 6, lane = t & 63;
    const int row = blockIdx.x*8 + w;           // same b for whole block
    const int b = row >> 10, i = row & (LQ - 1);

    for (int j = t; j < LQ; j += 512) {
        size_t base = ((size_t)(b*LQ + j))*42 + 3;   // atom 1 (CA)
        xs[j] = X[base+0]; ys[j] = X[base+1]; zs[j] = X[base+2];
        ms[j] = mask[b*LQ + j];
    }
    __syncthreads();

    const float mif = ms[i];
    const double cx = (double)xs[i], cy = (double)ys[i], cz = (double)zs[i];

    double Dk[16]; float mf[16];
    bool allone = (mif == 1.0f);
    #pragma unroll
    for (int s = 0; s < 16; ++s) {
        int j = s*64 + lane;
        double dx = __dsub_rn(cx, (double)xs[j]);
        double dy = __dsub_rn(cy, (double)ys[j]);
        double dz = __dsub_rn(cz, (double)zs[j]);
        mf[s] = ms[j];
        Dk[s] = __dadd_rn(__dadd_rn(__dmul_rn(dx,dx), __dmul_rn(dy,dy)),
                          __dmul_rn(dz,dz));
        allone = allone && (mf[s] == 1.0f);
    }

    if (!__all(allone ? 1 : 0)) {
        // exact general path: D = mi*mj*sqrt(ssq+1e-6); key = D + 2(1-m2)*max(D)
        const double mi_d = (double)mif;
        double lm = 0.0;
        #pragma unroll
        for (int s = 0; s < 16; ++s) {
            double m2 = __dmul_rn(mi_d, (double)mf[s]);
            Dk[s] = __dmul_rn(m2, sqrt(__dadd_rn(Dk[s], 1e-6)));
            lm = fmax(lm, Dk[s]);
        }
        #pragma unroll
        for (int off = 32; off; off >>= 1) lm = fmax(lm, __shfl_xor(lm, off));
        #pragma unroll
        for (int s = 0; s < 16; ++s) {
            double m2 = __dmul_rn(mi_d, (double)mf[s]);
            Dk[s] = __dadd_rn(Dk[s],
                    __dmul_rn(__dmul_rn(2.0, __dsub_rn(1.0, m2)), lm));
        }
    }

    ull key[16];
    #pragma unroll
    for (int s = 0; s < 16; ++s)
        key[s] = (((ull)__double_as_longlong(Dk[s])) & ~1023ull)
               | (unsigned)(s*64 + lane);

    for (int k = 0; k < KQ; ++k) {
        ull a0 = umin64(key[0],  key[1]),  a1 = umin64(key[2],  key[3]);
        ull a2 = umin64(key[4],  key[5]),  a3 = umin64(key[6],  key[7]);
        ull a4 = umin64(key[8],  key[9]),  a5 = umin64(key[10], key[11]);
        ull a6 = umin64(key[12], key[13]), a7 = umin64(key[14], key[15]);
        ull b0 = umin64(a0, a1), b1 = umin64(a2, a3);
        ull b2 = umin64(a4, a5), b3 = umin64(a6, a7);
        ull bk = umin64(umin64(b0, b1), umin64(b2, b3));
        #pragma unroll
        for (int off = 32; off; off >>= 1)
            bk = umin64(bk, (ull)__shfl_xor(bk, off));
        int j = (int)(bk & 1023ull);
        if (lane == 0) {
            int rg = row*KQ + k;
            idx_ws[rg] = j;
            out[EIDX_OFF + rg] = (float)j;
        }
        bool mine = ((j & 63) == lane);
        int s_win = j >> 6;
        #pragma unroll
        for (int s = 0; s < 16; ++s)
            key[s] = (mine && s == s_win) ? ~0ull : key[s];
    }
}

// ---------------------------------------------------------------------------
// Kernel B v16 = v12 + K-SPLIT waves. v12's LDS pipe measured ~99% busy
// (3840 cy demand vs 3874 cy chunk wall at 2 blocks/CU). 8 waves =
// 4 row-groups x 2 K-halves: each wave owns 32 rows x 128 cols x its 32-k
// half. Per thread-chunk: 2 gen_rbf (same as v12, no duplication), 8 b128
// B-reads (HALF of v12), 16 MFMA (same), ONE pair-address calc. Occupancy,
// staging, swizzle, gen math all v12-verbatim. Epilogue: lo/hi partial accs
// summed via 2-pass LDS exchange (scratch reuses atoms+Bl, 132-dword rows
// -> 2-way conflicts = free), then LN by lo waves. FP change = summation
// reorder only.
// ---------------------------------------------------------------------------
struct FusedSmem {
    alignas(16) unsigned short atoms[256*56];  // 28672 B (scaled+poisoned f16)
    alignas(16) unsigned short Bl[2*8192];     // 32768 B: dbuf W chunk, v7 swizzle
    alignas(16) float drow[MTILE];             // 512
    int residg[256];                           // 1024
    float gsh[EFQ], bsh[EFQ];                  // 1024
};                                             // 64,000 B -> 2 blocks/CU

// RBF features [8] for one (center-atom, neighbor-atom) pair, rbase folded
// into rboff. Poisoned coords (+/-30000) make all eight exp2 give exact +0.
static __device__ __forceinline__ void gen_rbf(
    const char* __restrict__ rowA, const char* __restrict__ rowB,
    int ao, int bo, float rboff, uint32_t* __restrict__ v)
{
    uint2 ca = *reinterpret_cast<const uint2*>(rowA + ao);
    uint2 nb = *reinterpret_cast<const uint2*>(rowB + bo);
    half2t c0 = __builtin_bit_cast(half2t, ca.x);
    half2t c1 = __builtin_bit_cast(half2t, ca.y);
    half2t n0 = __builtin_bit_cast(half2t, nb.x);
    half2t n1 = __builtin_bit_cast(half2t, nb.y);
    half2t dxy = c0 - n0;                        // v_pk_add_f16
    half2t dzw = c1 - n1;
    float dx = (float)dxy[0], dy = (float)dxy[1], dz = (float)dzw[0];
    float ssq = __fmaf_rn(dx, dx, __fmaf_rn(dy, dy,
                __fmaf_rn(dz, dz, 9.2332585e-7f)));     // (1e-6 scaled)
    float u = __builtin_amdgcn_sqrtf(ssq) + rboff;
    const float CJ[8] = {0.0f, 1.28119795f, 2.5623959f, 3.84359385f,
                         5.1247918f, 6.40598975f, 7.6871877f, 8.96838565f};
    #pragma unroll
    for (int k = 0; k < 4; ++k) {
        float t0 = u - CJ[2*k];
        float t1 = u - CJ[2*k+1];
        v[k] = pkh(__builtin_amdgcn_exp2f(-(t0*t0)),
                   __builtin_amdgcn_exp2f(-(t1*t1)));
    }
}

__global__ __launch_bounds__(512, 4) void fused_kernel(
    const float* __restrict__ X, const float* __restrict__ atom_mask,
    const _Float16* __restrict__ wpad, const float* __restrict__ gamma,
    const float* __restrict__ beta, const int* __restrict__ idx_ws,
    float* __restrict__ out)
{
    __shared__ FusedSmem sm;
    const int t = threadIdx.x;               // 0..511
    const int row0 = blockIdx.x * MTILE;
    const int b = row0 / (LQ*KQ);            // tiles never straddle b (30720 % 128 == 0)

    if (t < MTILE) {
        int rg = row0 + t;
        int rem = rg - b*(LQ*KQ);
        int i = rem / KQ;
        int j = idx_ws[rg];
        sm.residg[t]       = b*LQ + i;
        sm.residg[MTILE+t] = b*LQ + j;
        sm.drow[t] = (float)j - (float)i;
    }
    if (t < EFQ) { sm.gsh[t] = gamma[t]; sm.bsh[t] = beta[t]; }
    __syncthreads();

    const int w = t >> 6, lane = t & 63, q = lane >> 4, l15 = lane & 15;
    const int kh = w >> 2, wr = w & 3;        // K-half x row-group
    const int m0 = wr*32 + l15, m1 = m0 + 16;

    // ---- staging hoists (v12 verbatim: 8 waves x 2 regions, dbuf) --------
    int stRegion[2]; const _Float16* stBase[2];
    #pragma unroll
    for (int i2 = 0; i2 < 2; ++i2) {
        int region = w*2 + i2;                        // 16 regions x 8 rows
        int n = region*8 + (lane >> 3);
        int kbsrc = (lane & 7) ^ (lane >> 3);
        stRegion[i2] = region;
        stBase[i2] = wpad + (size_t)n*KPAD + kbsrc*8;
    }
    auto stage = [&](int c) {
        #pragma unroll
        for (int i2 = 0; i2 < 2; ++i2) {
            const _Float16* g = stBase[i2] + c*64;
            __builtin_amdgcn_global_load_lds(
                (const __attribute__((address_space(1))) uint32_t*)g,
                (__attribute__((address_space(3))) uint32_t*)
                    &sm.Bl[((c & 1) << 13) + stRegion[i2]*512],
                16, 0, 0);
        }
    };
    stage(0);                                 // flies across the prologue

    // stage atoms: fp32 global -> packed f16 LDS (raw, x,y,z,0 per slot)
    for (int u2 = t; u2 < 256*14; u2 += 512) {   // 7 exact iterations
        int s = u2 / 14; int a = u2 - s*14;
        const float* xp = X + (size_t)sm.residg[s]*42 + a*3;
        uint2 pk; pk.x = pkh(xp[0], xp[1]); pk.y = pkh(xp[2], 0.0f);
        *reinterpret_cast<uint2*>(&sm.atoms[s*56 + a*4]) = pk;
    }
    __syncthreads();

    if (t < 256) {   // Cb (raw) into slot 4, then scale + mask-poison all 14
        unsigned short* at = &sm.atoms[t*56];
        auto ld3 = [&](int slot, float& x, float& y, float& z) {
            half2t p0 = *reinterpret_cast<const half2t*>(at + slot*4);
            half2t p1 = *reinterpret_cast<const half2t*>(at + slot*4 + 2);
            x = (float)p0[0]; y = (float)p0[1]; z = (float)p1[0];
        };
        float Nx,Ny,Nz, Cax,Cay,Caz, Cx,Cy,Cz;
        ld3(0, Nx,Ny,Nz); ld3(1, Cax,Cay,Caz); ld3(2, Cx,Cy,Cz);
        float bx=Cax-Nx, by=Cay-Ny, bz=Caz-Nz;
        float ex=Cx-Cax, ey=Cy-Cay, ez=Cz-Caz;
        float ax = by*ez - bz*ey, ay = bz*ex - bx*ez, az = bx*ey - by*ex;
        float cbx = -0.58273431f*ax + 0.56802827f*bx - 0.54067466f*ex + Cax;
        float cby = -0.58273431f*ay + 0.56802827f*by - 0.54067466f*ey + Cay;
        float cbz = -0.58273431f*az + 0.56802827f*bz - 0.54067466f*ez + Caz;
        uint2 pk4; pk4.x = pkh(cbx, cby); pk4.y = pkh(cbz, 0.0f);
        *reinterpret_cast<uint2*>(at + 4*4) = pk4;   // slot 4 = Cb (raw)

        const float P = (t < MTILE) ? 30000.0f : -30000.0f;  // center/neighbor
        const uint32_t pxx = pkh(P, P), pxy = pkh(P, 0.0f);
        half2t sc2; sc2[0] = (_Float16)0.96089846f; sc2[1] = (_Float16)0.96089846f;
        const float* amp = &atom_mask[(size_t)sm.residg[t]*AQ];
        #pragma unroll
        for (int a = 0; a < AQ; ++a) {
            uint2 vv = *reinterpret_cast<const uint2*>(at + a*4);
            half2t lo = __builtin_bit_cast(half2t, vv.x) * sc2;
            half2t hi = __builtin_bit_cast(half2t, vv.y) * sc2;
            bool msk = amp[a] > 0.5f;
            uint2 ov;
            ov.x = msk ? pxx : __builtin_bit_cast(uint32_t, lo);
            ov.y = msk ? pxy : __builtin_bit_cast(uint32_t, hi);
            *reinterpret_cast<uint2*>(at + a*4) = ov;
        }
    }

    // ---- B-read LDS offsets: k-slot ks = kh*4 + q (wave's own K-half) ----
    int boff[8];
    #pragma unroll
    for (int nt = 0; nt < 8; ++nt) {
        int n = nt*16 + l15;
        boff[nt] = n*64 + (((kh*4 + q) ^ (n&7))*8);
    }

    const char* rowA0 = (const char*)&sm.atoms[m0*56];
    const char* rowB0 = (const char*)&sm.atoms[(MTILE+m0)*56];
    const char* rowA1 = (const char*)&sm.atoms[m1*56];
    const char* rowB1 = (const char*)&sm.atoms[(MTILE+m1)*56];
    const int   qlt2  = (q < 2) ? 1 : 0;
    const int   pbase = 2*kh - qlt2;          // pair p = 4c + pbase
    const float rboff = -(float)((q & 1) * 8) * 1.28119795f;

    floatx4 acc0[8], acc1[8];
    #pragma unroll
    for (int nt = 0; nt < 8; ++nt) {
        acc0[nt] = (floatx4){0.f,0.f,0.f,0.f};
        acc1[nt] = (floatx4){0.f,0.f,0.f,0.f};
    }

    __syncthreads();   // atoms scaled/poisoned visible; stage(0) drained

    union H8 { uint32_t u[4]; half8 h; };
    for (int c = 0; c < NCHUNK; ++c) {
        if (c < NCHUNK-1) stage(c+1);         // dbuf DMA, lands by bottom barrier

        H8 a0, a1;                            // same f0 for both rows
        if (c == 0 && kh == 0 && qlt2) {      // positional features (f0 = 0 or 8)
            const float fr[8] = {1.0f, 0.31622776601683794f, 0.1f,
                0.031622776601683794f, 0.01f, 0.0031622776601683794f,
                0.001f, 0.00031622776601683794f};
            float dr0 = sm.drow[m0], dr1 = sm.drow[m1];
            float e0[8], e1[8];
            if (q == 0) {
                #pragma unroll
                for (int j = 0; j < 8; ++j) { e0[j] = __cosf(dr0 * fr[j]); e1[j] = __cosf(dr1 * fr[j]); }
            } else {
                #pragma unroll
                for (int j = 0; j < 8; ++j) { e0[j] = __sinf(dr0 * fr[j]); e1[j] = __sinf(dr1 * fr[j]); }
            }
            #pragma unroll
            for (int k = 0; k < 4; ++k) {
                a0.u[k] = pkh(e0[2*k], e0[2*k+1]);
                a1.u[k] = pkh(e1[2*k], e1[2*k+1]);
            }
        } else {
            int p  = 4*c + pbase;
            int pa = (p * 74899) >> 20;
            pa = pa > 13 ? 13 : pa;
            int ao = pa << 3, bo = (p - pa*14) << 3;   // v12 pad-read semantics
            gen_rbf(rowA0, rowB0, ao, bo, rboff, a0.u);
            gen_rbf(rowA1, rowB1, ao, bo, rboff, a1.u);
        }

        const unsigned short* Bb = &sm.Bl[(c & 1) << 13];
        #pragma unroll
        for (int nt = 0; nt < 8; ++nt) {
            half8 bv = *reinterpret_cast<const half8*>(&Bb[boff[nt]]);
            acc0[nt] = __builtin_amdgcn_mfma_f32_16x16x32_f16(a0.h, bv, acc0[nt], 0, 0, 0);
            acc1[nt] = __builtin_amdgcn_mfma_f32_16x16x32_f16(a1.h, bv, acc1[nt], 0, 0, 0);
        }
        __syncthreads();   // drains stage DMA; fences Bl[c&1] reads before restage
    }

    // ---- K-split reduction + LayerNorm. scratch reuses atoms+Bl region ----
    // 2 passes x 64 rows x 132 dwords = 33792 B < 61440 B (atoms+Bl).
    // C/D layout: col = l15, row = q*4 + v within 16-row group g.
    float* scr = reinterpret_cast<float*>(sm.atoms);
    #pragma unroll
    for (int pass = 0; pass < 2; ++pass) {
        if ((wr >> 1) == pass && kh == 1) {     // hi waves: dump partials
            #pragma unroll
            for (int v = 0; v < 4; ++v) {
                int r0 = (wr & 1)*32 + q*4 + v;          // g=0 rows
                int r1 = r0 + 16;                        // g=1 rows
                #pragma unroll
                for (int nt = 0; nt < 8; ++nt) {
                    scr[r0*132 + nt*16 + l15] = acc0[nt][v];
                    scr[r1*132 + nt*16 + l15] = acc1[nt][v];
                }
            }
        }
        __syncthreads();
        if ((wr >> 1) == pass && kh == 0) {     // lo waves: add + LN + store
            #pragma unroll
            for (int g = 0; g < 2; ++g) {
                #pragma unroll
                for (int v = 0; v < 4; ++v) {
                    int rloc = (wr & 1)*32 + g*16 + q*4 + v;
                    float s = 0.f, s2 = 0.f;
                    float xv[8];
                    #pragma unroll
                    for (int nt = 0; nt < 8; ++nt) {
                        float x = (g ? acc1[nt][v] : acc0[nt][v])
                                + scr[rloc*132 + nt*16 + l15];
                        xv[nt] = x; s += x; s2 += x*x;
                    }
                    #pragma unroll
                    for (int off = 1; off < 16; off <<= 1) {
                        s  += __shfl_xor(s,  off);
                        s2 += __shfl_xor(s2, off);
                    }
                    float mean = s * (1.0f/128.0f);
                    float var  = s2 * (1.0f/128.0f) - mean*mean;
                    float rstd = 1.0f / sqrtf(var + 1e-5f);
                    int row_l = wr*32 + g*16 + q*4 + v;
                    size_t obase = (size_t)(row0 + row_l)*EFQ;
                    #pragma unroll
                    for (int nt = 0; nt < 8; ++nt) {
                        int col = nt*16 + l15;
                        out[obase + col] = (xv[nt] - mean)*rstd*sm.gsh[col] + sm.bsh[col];
                    }
                }
            }
        }
        __syncthreads();                        // scr free for next pass
    }
}

extern "C" void kernel_launch(void* const* d_in, const int* in_sizes, int n_in,
                              void* d_out, int out_size, void* d_ws, size_t ws_size,
                              hipStream_t stream)
{
    const float* X         = (const float*)d_in[0];
    const float* mask      = (const float*)d_in[1];
    // d_in[2] residue_idx, d_in[3] chain_labels: unused by the reference math
    const float* atom_mask = (const float*)d_in[4];
    const float* W         = (const float*)d_in[5];
    const float* gamma     = (const float*)d_in[6];
    const float* beta      = (const float*)d_in[7];
    float* out = (float*)d_out;

    int*       idx_ws = (int*)d_ws;                               // 61440*4 B
    _Float16*  wpad   = (_Float16*)((char*)d_ws + 262144);        // 128*3200*2 B

    hipLaunchKernelGGL(topk_kernel, dim3(306), dim3(512), 0, stream,
                       X, mask, W, out, idx_ws, wpad);
    hipLaunchKernelGGL(fused_kernel, dim3(ROWS/MTILE), dim3(512), 0, stream,
                       X, atom_mask, wpad, gamma, beta, idx_ws, out);
}

// Round 11
// 168.457 us; speedup vs baseline: 1.8254x; 1.0321x over previous
//
#include <hip/hip_runtime.h>
#include <hip/hip_bf16.h>
#include <stdint.h>

#define LQ 1024
#define BQ 2
#define AQ 14
#define KQ 30
#define EFQ 128
#define EDGE_IN 3152
#define KPAD 3200
#define NCHUNK 50
#define MTILE 128
#define ROWS (BQ*LQ*KQ)            /* 61440 */
#define EIDX_OFF (ROWS*EFQ)        /* 7864320 */

typedef __attribute__((ext_vector_type(8))) _Float16 half8;
typedef __attribute__((ext_vector_type(2))) _Float16 half2t;
typedef __attribute__((ext_vector_type(4))) float floatx4;
typedef unsigned long long ull;

static __device__ __forceinline__ uint32_t pkh(float a, float b) {
    auto h = __builtin_amdgcn_cvt_pkrtz(a, b);   // __fp16 ext_vector(2)
    return __builtin_bit_cast(uint32_t, h);
}
static __device__ __forceinline__ ull umin64(ull a, ull b) { return a < b ? a : b; }

// ---------------------------------------------------------------------------
// Kernel A v6 (unchanged): blocks 0..255 topk (8 rows/block, one wave per row,
// u64-packed keys); blocks 256..305: W fp32 -> f16 padded copy.
// ---------------------------------------------------------------------------
__global__ __launch_bounds__(512) void topk_kernel(
    const float* __restrict__ X, const float* __restrict__ mask,
    const float* __restrict__ W, float* __restrict__ out,
    int* __restrict__ idx_ws, _Float16* __restrict__ wpad)
{
    __shared__ float xs[LQ], ys[LQ], zs[LQ], ms[LQ];
    const int t = threadIdx.x;

    if (blockIdx.x >= 256) {                    // ---- merged wpad ----
        int base = (blockIdx.x - 256)*8192 + t; // 50 blocks x 8192 = 409600 exact
        #pragma unroll
        for (int r = 0; r < 16; ++r) {
            int idx = base + r*512;
            int n = idx / KPAD, f = idx - n*KPAD;
            float v = (f < EDGE_IN) ? W[(size_t)n*EDGE_IN + f] : 0.0f;
            wpad[idx] = (_Float16)v;
        }
        return;
    }

    const int w = t >> 6, lane = t & 63;
    const int row = blockIdx.x*8 + w;           // same b for whole block
    const int b = row >> 10, i = row & (LQ - 1);

    for (int j = t; j < LQ; j += 512) {
        size_t base = ((size_t)(b*LQ + j))*42 + 3;   // atom 1 (CA)
        xs[j] = X[base+0]; ys[j] = X[base+1]; zs[j] = X[base+2];
        ms[j] = mask[b*LQ + j];
    }
    __syncthreads();

    const float mif = ms[i];
    const double cx = (double)xs[i], cy = (double)ys[i], cz = (double)zs[i];

    double Dk[16]; float mf[16];
    bool allone = (mif == 1.0f);
    #pragma unroll
    for (int s = 0; s < 16; ++s) {
        int j = s*64 + lane;
        double dx = __dsub_rn(cx, (double)xs[j]);
        double dy = __dsub_rn(cy, (double)ys[j]);
        double dz = __dsub_rn(cz, (double)zs[j]);
        mf[s] = ms[j];
        Dk[s] = __dadd_rn(__dadd_rn(__dmul_rn(dx,dx), __dmul_rn(dy,dy)),
                          __dmul_rn(dz,dz));
        allone = allone && (mf[s] == 1.0f);
    }

    if (!__all(allone ? 1 : 0)) {
        // exact general path: D = mi*mj*sqrt(ssq+1e-6); key = D + 2(1-m2)*max(D)
        const double mi_d = (double)mif;
        double lm = 0.0;
        #pragma unroll
        for (int s = 0; s < 16; ++s) {
            double m2 = __dmul_rn(mi_d, (double)mf[s]);
            Dk[s] = __dmul_rn(m2, sqrt(__dadd_rn(Dk[s], 1e-6)));
            lm = fmax(lm, Dk[s]);
        }
        #pragma unroll
        for (int off = 32; off; off >>= 1) lm = fmax(lm, __shfl_xor(lm, off));
        #pragma unroll
        for (int s = 0; s < 16; ++s) {
            double m2 = __dmul_rn(mi_d, (double)mf[s]);
            Dk[s] = __dadd_rn(Dk[s],
                    __dmul_rn(__dmul_rn(2.0, __dsub_rn(1.0, m2)), lm));
        }
    }

    ull key[16];
    #pragma unroll
    for (int s = 0; s < 16; ++s)
        key[s] = (((ull)__double_as_longlong(Dk[s])) & ~1023ull)
               | (unsigned)(s*64 + lane);

    for (int k = 0; k < KQ; ++k) {
        ull a0 = umin64(key[0],  key[1]),  a1 = umin64(key[2],  key[3]);
        ull a2 = umin64(key[4],  key[5]),  a3 = umin64(key[6],  key[7]);
        ull a4 = umin64(key[8],  key[9]),  a5 = umin64(key[10], key[11]);
        ull a6 = umin64(key[12], key[13]), a7 = umin64(key[14], key[15]);
        ull b0 = umin64(a0, a1), b1 = umin64(a2, a3);
        ull b2 = umin64(a4, a5), b3 = umin64(a6, a7);
        ull bk = umin64(umin64(b0, b1), umin64(b2, b3));
        #pragma unroll
        for (int off = 32; off; off >>= 1)
            bk = umin64(bk, (ull)__shfl_xor(bk, off));
        int j = (int)(bk & 1023ull);
        if (lane == 0) {
            int rg = row*KQ + k;
            idx_ws[rg] = j;
            out[EIDX_OFF + rg] = (float)j;
        }
        bool mine = ((j & 63) == lane);
        int s_win = j >> 6;
        #pragma unroll
        for (int s = 0; s < 16; ++s)
            key[s] = (mine && s == s_win) ? ~0ull : key[s];
    }
}

// ---------------------------------------------------------------------------
// Kernel B v12 (REINSTATED -- session best, 80.7 us fused / 170.2 us total).
// Structural constraint (R9): no HW pipe saturated (VALU ~54%, LDS ~50%,
// MFMA ~25%, HBM ~6%); wall = per-chunk serial gen->MFMA dependency chain +
// vmcnt(0)-drain barrier at 16 waves/CU. Five alternative decompositions
// (col-split v11, row-split v8/v15, K-split v16, direct-L2 v9/v13/v14) all
// measured >= this config; it minimizes barriers (50) without duplicating
// trans-pipe gen work and keeps the register allocator at 56 VGPR.
//  - masked atoms poisoned to +/-30000 in LDS coords -> exp2 underflows to +0
//  - coords pre-scaled by 0.96089846 at staging (after Cb); eps' = 9.2333e-7
//  - pair addressing via p0 = 4c-(q<2), p1 = p0+2, one magic-mul each
//  - double-buffered Bl, ONE __syncthreads per chunk at loop bottom
// LDS 64.0 KB -> 2 blocks/CU (16 waves/CU).
// ---------------------------------------------------------------------------
struct FusedSmem {
    alignas(16) unsigned short atoms[256*56];  // 28672 B: f16 x,y,z,pad x 14 slots (scaled+poisoned)
    alignas(16) unsigned short Bl[2*8192];     // 32768 B: dbuf W chunk (f16), v7 XOR swizzle
    alignas(16) float drow[MTILE];             // 512
    int residg[256];                           // 1024
    float gsh[EFQ], bsh[EFQ];                  // 1024
};                                             // 64,000 B

// RBF features [8] for one (center-atom, neighbor-atom) pair, rbase folded
// into rboff: t_j = (|d|_scaled + rboff) - j*1.28119795; e = exp2(-t^2).
// Poisoned coords make |d| ~ 3e4..1e5 -> all eight exp2 give exact +0.
static __device__ __forceinline__ void gen_rbf(
    const char* __restrict__ rowA, const char* __restrict__ rowB,
    int ao, int bo, float rboff, uint32_t* __restrict__ v)
{
    uint2 ca = *reinterpret_cast<const uint2*>(rowA + ao);
    uint2 nb = *reinterpret_cast<const uint2*>(rowB + bo);
    half2t c0 = __builtin_bit_cast(half2t, ca.x);
    half2t c1 = __builtin_bit_cast(half2t, ca.y);
    half2t n0 = __builtin_bit_cast(half2t, nb.x);
    half2t n1 = __builtin_bit_cast(half2t, nb.y);
    half2t dxy = c0 - n0;                        // v_pk_add_f16
    half2t dzw = c1 - n1;
    float dx = (float)dxy[0], dy = (float)dxy[1], dz = (float)dzw[0];
    float ssq = __fmaf_rn(dx, dx, __fmaf_rn(dy, dy,
                __fmaf_rn(dz, dz, 9.2332585e-7f)));     // (1e-6 scaled)
    float u = __builtin_amdgcn_sqrtf(ssq) + rboff;
    const float CJ[8] = {0.0f, 1.28119795f, 2.5623959f, 3.84359385f,
                         5.1247918f, 6.40598975f, 7.6871877f, 8.96838565f};
    #pragma unroll
    for (int k = 0; k < 4; ++k) {
        float t0 = u - CJ[2*k];
        float t1 = u - CJ[2*k+1];
        v[k] = pkh(__builtin_amdgcn_exp2f(-(t0*t0)),
                   __builtin_amdgcn_exp2f(-(t1*t1)));
    }
}

__global__ __launch_bounds__(512) void fused_kernel(
    const float* __restrict__ X, const float* __restrict__ atom_mask,
    const _Float16* __restrict__ wpad, const float* __restrict__ gamma,
    const float* __restrict__ beta, const int* __restrict__ idx_ws,
    float* __restrict__ out)
{
    __shared__ FusedSmem sm;
    const int t = threadIdx.x;               // 0..511
    const int row0 = blockIdx.x * MTILE;
    const int b = row0 / (LQ*KQ);            // tiles never straddle b (30720 % 128 == 0)

    if (t < MTILE) {
        int rg = row0 + t;
        int rem = rg - b*(LQ*KQ);
        int i = rem / KQ;
        int j = idx_ws[rg];
        sm.residg[t]       = b*LQ + i;
        sm.residg[MTILE+t] = b*LQ + j;
        sm.drow[t] = (float)j - (float)i;
    }
    if (t < EFQ) { sm.gsh[t] = gamma[t]; sm.bsh[t] = beta[t]; }
    __syncthreads();

    const int w = t >> 6, lane = t & 63, q = lane >> 4, l15 = lane & 15;
    const int m = w*16 + l15;                 // tile-local row (0..127)

    // ---- staging hoists (v7 verbatim + dbuf select) ----------------------
    int stRegion[2]; const _Float16* stBase[2];
    #pragma unroll
    for (int i2 = 0; i2 < 2; ++i2) {
        int region = w*2 + i2;                        // 16 regions x 8 rows
        int n = region*8 + (lane >> 3);
        int kbsrc = (lane & 7) ^ (lane >> 3);
        stRegion[i2] = region;
        stBase[i2] = wpad + (size_t)n*KPAD + kbsrc*8;
    }
    auto stage = [&](int c) {
        #pragma unroll
        for (int i2 = 0; i2 < 2; ++i2) {
            const _Float16* g = stBase[i2] + c*64;
            __builtin_amdgcn_global_load_lds(
                (const __attribute__((address_space(1))) uint32_t*)g,
                (__attribute__((address_space(3))) uint32_t*)
                    &sm.Bl[((c & 1) << 13) + stRegion[i2]*512],
                16, 0, 0);
        }
    };
    stage(0);                                 // flies across the prologue

    // stage atoms: fp32 global -> packed f16 LDS (raw, x,y,z,0 per slot)
    for (int u2 = t; u2 < 256*14; u2 += 512) {   // 7 exact iterations
        int s = u2 / 14; int a = u2 - s*14;
        const float* xp = X + (size_t)sm.residg[s]*42 + a*3;
        uint2 pk; pk.x = pkh(xp[0], xp[1]); pk.y = pkh(xp[2], 0.0f);
        *reinterpret_cast<uint2*>(&sm.atoms[s*56 + a*4]) = pk;
    }
    __syncthreads();

    if (t < 256) {   // Cb (raw) into slot 4, then scale + mask-poison all 14
        unsigned short* at = &sm.atoms[t*56];
        auto ld3 = [&](int slot, float& x, float& y, float& z) {
            half2t p0 = *reinterpret_cast<const half2t*>(at + slot*4);
            half2t p1 = *reinterpret_cast<const half2t*>(at + slot*4 + 2);
            x = (float)p0[0]; y = (float)p0[1]; z = (float)p1[0];
        };
        float Nx,Ny,Nz, Cax,Cay,Caz, Cx,Cy,Cz;
        ld3(0, Nx,Ny,Nz); ld3(1, Cax,Cay,Caz); ld3(2, Cx,Cy,Cz);
        float bx=Cax-Nx, by=Cay-Ny, bz=Caz-Nz;
        float ex=Cx-Cax, ey=Cy-Cay, ez=Cz-Caz;
        float ax = by*ez - bz*ey, ay = bz*ex - bx*ez, az = bx*ey - by*ex;
        float cbx = -0.58273431f*ax + 0.56802827f*bx - 0.54067466f*ex + Cax;
        float cby = -0.58273431f*ay + 0.56802827f*by - 0.54067466f*ey + Cay;
        float cbz = -0.58273431f*az + 0.56802827f*bz - 0.54067466f*ez + Caz;
        uint2 pk4; pk4.x = pkh(cbx, cby); pk4.y = pkh(cbz, 0.0f);
        *reinterpret_cast<uint2*>(at + 4*4) = pk4;   // slot 4 = Cb (raw)

        const float P = (t < MTILE) ? 30000.0f : -30000.0f;  // center/neighbor
        const uint32_t pxx = pkh(P, P), pxy = pkh(P, 0.0f);
        half2t sc2; sc2[0] = (_Float16)0.96089846f; sc2[1] = (_Float16)0.96089846f;
        const float* amp = &atom_mask[(size_t)sm.residg[t]*AQ];
        #pragma unroll
        for (int a = 0; a < AQ; ++a) {
            uint2 vv = *reinterpret_cast<const uint2*>(at + a*4);
            half2t lo = __builtin_bit_cast(half2t, vv.x) * sc2;
            half2t hi = __builtin_bit_cast(half2t, vv.y) * sc2;
            bool msk = amp[a] > 0.5f;
            uint2 ov;
            ov.x = msk ? pxx : __builtin_bit_cast(uint32_t, lo);
            ov.y = msk ? pxy : __builtin_bit_cast(uint32_t, hi);
            *reinterpret_cast<uint2*>(at + a*4) = ov;
        }
    }

    // ---- B-read LDS offsets (v7 swizzle) ---------------------------------
    int boff0[8], boff1[8];
    #pragma unroll
    for (int nt = 0; nt < 8; ++nt) {
        int n = nt*16 + l15;
        boff0[nt] = n*64 + ((q ^ (n&7))*8);
        boff1[nt] = n*64 + (((4+q) ^ (n&7))*8);
    }

    const char* rowA = (const char*)&sm.atoms[m*56];
    const char* rowB = (const char*)&sm.atoms[(MTILE+m)*56];
    const int   qlt2  = (q < 2) ? 1 : 0;
    const float rboff = -(float)((q & 1) * 8) * 1.28119795f;

    floatx4 acc[8];
    #pragma unroll
    for (int nt = 0; nt < 8; ++nt) acc[nt] = (floatx4){0.f,0.f,0.f,0.f};

    __syncthreads();   // atoms scaled/poisoned visible; stage(0) drained

    union H8 { uint32_t u[4]; half8 h; };
    for (int c = 0; c < NCHUNK; ++c) {
        if (c < NCHUNK-1) stage(c+1);         // lands during gen+MFMA below

        // pair addressing: p0 = 4c - (q<2), p1 = p0 + 2; a = p/14, bp = p%14
        int p0 = 4*c - qlt2;
        int p1 = p0 + 2;
        int pa0 = (p0 * 74899) >> 20;  int pa1 = (p1 * 74899) >> 20;
        pa0 = pa0 > 13 ? 13 : pa0;     pa1 = pa1 > 13 ? 13 : pa1;
        int ao0 = pa0 << 3, bo0 = (p0 - pa0*14) << 3;
        int ao1 = pa1 << 3, bo1 = (p1 - pa1*14) << 3;

        H8 a00, a01;
        if (c == 0) {
            if (qlt2) {                        // positional features (f0 = 0 or 8)
                const float fr[8] = {1.0f, 0.31622776601683794f, 0.1f,
                    0.031622776601683794f, 0.01f, 0.0031622776601683794f,
                    0.001f, 0.00031622776601683794f};
                float dr = sm.drow[m];
                float e[8];
                if (q == 0) {
                    #pragma unroll
                    for (int j = 0; j < 8; ++j) e[j] = __cosf(dr * fr[j]);
                } else {
                    #pragma unroll
                    for (int j = 0; j < 8; ++j) e[j] = __sinf(dr * fr[j]);
                }
                #pragma unroll
                for (int k = 0; k < 4; ++k) a00.u[k] = pkh(e[2*k], e[2*k+1]);
            } else {
                gen_rbf(rowA, rowB, ao0, bo0, rboff, a00.u);
            }
        } else {
            gen_rbf(rowA, rowB, ao0, bo0, rboff, a00.u);
        }
        gen_rbf(rowA, rowB, ao1, bo1, rboff, a01.u);

        const unsigned short* Bb = &sm.Bl[(c & 1) << 13];
        #pragma unroll
        for (int nt = 0; nt < 8; ++nt) {
            half8 b0 = *reinterpret_cast<const half8*>(&Bb[boff0[nt]]);
            half8 b1 = *reinterpret_cast<const half8*>(&Bb[boff1[nt]]);
            acc[nt] = __builtin_amdgcn_mfma_f32_16x16x32_f16(a00.h, b0, acc[nt], 0, 0, 0);
            acc[nt] = __builtin_amdgcn_mfma_f32_16x16x32_f16(a01.h, b1, acc[nt], 0, 0, 0);
        }
        __syncthreads();   // drains my stage(c+1) DMA (vmcnt 0) + fences
                           // everyone's reads of Bl[c&1] before it is restaged
    }

    // LayerNorm epilogue. C/D layout: col = lane&15, row = quad*4 + reg.
    #pragma unroll
    for (int v = 0; v < 4; ++v) {
        float s = 0.f, s2 = 0.f;
        #pragma unroll
        for (int nt = 0; nt < 8; ++nt) { float x = acc[nt][v]; s += x; s2 += x*x; }
        #pragma unroll
        for (int off = 1; off < 16; off <<= 1) {
            s  += __shfl_xor(s,  off);
            s2 += __shfl_xor(s2, off);
        }
        float mean = s * (1.0f/128.0f);
        float var  = s2 * (1.0f/128.0f) - mean*mean;
        float rstd = 1.0f / sqrtf(var + 1e-5f);
        int row_l = w*16 + q*4 + v;
        size_t obase = (size_t)(row0 + row_l)*EFQ;
        #pragma unroll
        for (int nt = 0; nt < 8; ++nt) {
            int col = nt*16 + l15;
            out[obase + col] = (acc[nt][v] - mean)*rstd*sm.gsh[col] + sm.bsh[col];
        }
    }
}

extern "C" void kernel_launch(void* const* d_in, const int* in_sizes, int n_in,
                              void* d_out, int out_size, void* d_ws, size_t ws_size,
                              hipStream_t stream)
{
    const float* X         = (const float*)d_in[0];
    const float* mask      = (const float*)d_in[1];
    // d_in[2] residue_idx, d_in[3] chain_labels: unused by the reference math
    const float* atom_mask = (const float*)d_in[4];
    const float* W         = (const float*)d_in[5];
    const float* gamma     = (const float*)d_in[6];
    const float* beta      = (const float*)d_in[7];
    float* out = (float*)d_out;

    int*       idx_ws = (int*)d_ws;                               // 61440*4 B
    _Float16*  wpad   = (_Float16*)((char*)d_ws + 262144);        // 128*3200*2 B

    hipLaunchKernelGGL(topk_kernel, dim3(306), dim3(512), 0, stream,
                       X, mask, W, out, idx_ws, wpad);
    hipLaunchKernelGGL(fused_kernel, dim3(ROWS/MTILE), dim3(512), 0, stream,
                       X, atom_mask, wpad, gamma, beta, idx_ws, out);
}